// Round 1
// baseline (74.064 us; speedup 1.0000x reference)
//
#include <hip/hip_runtime.h>
#include <hip/hip_bf16.h>

// Shapes (fixed by the reference): B=8, C=32, H=64, W=512, NCHW layout.
#define CH   32
#define WD   512
#define NH   64
#define CHST (NH * WD)      // stride between channels        = 32768 floats
#define BST  (CH * CHST)    // stride between batch elements  = 1048576 floats
#define ROWP 520            // bf16 LDS row stride: 1040 B = 16B-aligned, 4-bank skew

__device__ __forceinline__ unsigned short f2bf(float f) {
  union { __hip_bfloat16 h; unsigned short u; } cv;
  cv.h = __float2bfloat16(f);
  return cv.u;
}

__device__ __forceinline__ void bf2(unsigned int u, float& lo, float& hi) {
  lo = __uint_as_float(u << 16);
  hi = __uint_as_float(u & 0xffff0000u);
}

// One workgroup per (b,h): full attention over W=512 pixels, C=32 channels.
// Math: M[o][c] = sum_x kp[x][o]*vp[x][c];  G[cp][c] = sum_o wq[o][cp]*M[o][c] + (cp==c);
//       g[c] = sum_o bq[o]*M[o][c];         out[c][x] = sum_cp q[cp][x]*G[cp][c] + g[c]
// (residual folded into G's diagonal).
__global__ __launch_bounds__(512, 4)
void fused_mha(const float* __restrict__ q, const float* __restrict__ k,
               const float* __restrict__ v,
               const float* __restrict__ wq, const float* __restrict__ bq,
               const float* __restrict__ wk, const float* __restrict__ bk,
               const float* __restrict__ wv, const float* __restrict__ bv,
               float* __restrict__ out)
{
  __shared__ unsigned short kp_t[CH][ROWP];  // kp_t[o][x], bf16 bits
  __shared__ unsigned short vp_t[CH][ROWP];  // vp_t[c][x], bf16 bits
  __shared__ float M_t[CH][36];              // M_t[c][o] = M[o][c]  (36: 16B-aligned rows, bank skew)
  __shared__ float G_t[CH][CH];              // G_t[c][cp] = G[cp][c] (rows read as broadcast b128)
  __shared__ float g_l[CH];

  const int t  = threadIdx.x;          // 0..511
  const int bh = blockIdx.x;           // 0..511  (b*64 + h)
  const size_t base = (size_t)(bh >> 6) * BST + (size_t)(bh & 63) * WD;
  const int x = t;                     // pixel owned in phases 1 & 3

  float col[CH];

  // ---------------- Phase 1: project k and v for pixel x; store bf16, transposed ----
  #pragma unroll
  for (int c = 0; c < CH; ++c) col[c] = k[base + (size_t)c * CHST + x];
  #pragma unroll
  for (int o = 0; o < CH; ++o) {
    float acc = bk[o];
    const float4* wr = (const float4*)(wk + o * CH);  // uniform address -> s_load
    #pragma unroll
    for (int c4 = 0; c4 < CH / 4; ++c4) {
      float4 w4 = wr[c4];
      acc = fmaf(w4.x, col[4*c4+0], acc);
      acc = fmaf(w4.y, col[4*c4+1], acc);
      acc = fmaf(w4.z, col[4*c4+2], acc);
      acc = fmaf(w4.w, col[4*c4+3], acc);
    }
    kp_t[o][x] = f2bf(acc);
  }

  #pragma unroll
  for (int c = 0; c < CH; ++c) col[c] = v[base + (size_t)c * CHST + x];
  #pragma unroll
  for (int o = 0; o < CH; ++o) {
    float acc = bv[o];
    const float4* wr = (const float4*)(wv + o * CH);
    #pragma unroll
    for (int c4 = 0; c4 < CH / 4; ++c4) {
      float4 w4 = wr[c4];
      acc = fmaf(w4.x, col[4*c4+0], acc);
      acc = fmaf(w4.y, col[4*c4+1], acc);
      acc = fmaf(w4.z, col[4*c4+2], acc);
      acc = fmaf(w4.w, col[4*c4+3], acc);
    }
    vp_t[o][x] = f2bf(acc);
  }

  __syncthreads();

  // ---------------- Phase 2: M[c1][c2] & M[c1][c2+1]; thread owns (c1, c2-pair) -----
  {
    const int c1 = t >> 4;             // 0..31
    const int c2 = (t & 15) << 1;      // 0,2,..,30
    const uint4* krow  = (const uint4*)(&kp_t[c1][0]);
    const uint4* vrow0 = (const uint4*)(&vp_t[c2][0]);
    const uint4* vrow1 = (const uint4*)(&vp_t[c2 + 1][0]);
    float m0 = 0.f, m1 = 0.f;
    #pragma unroll 4
    for (int i = 0; i < WD / 8; ++i) {       // 8 pixels per iteration
      uint4 ku = krow[i];
      uint4 a0 = vrow0[i];
      uint4 a1 = vrow1[i];
      float kl, kh, al, ah;
      bf2(ku.x, kl, kh);
      bf2(a0.x, al, ah); m0 = fmaf(kl, al, m0); m0 = fmaf(kh, ah, m0);
      bf2(a1.x, al, ah); m1 = fmaf(kl, al, m1); m1 = fmaf(kh, ah, m1);
      bf2(ku.y, kl, kh);
      bf2(a0.y, al, ah); m0 = fmaf(kl, al, m0); m0 = fmaf(kh, ah, m0);
      bf2(a1.y, al, ah); m1 = fmaf(kl, al, m1); m1 = fmaf(kh, ah, m1);
      bf2(ku.z, kl, kh);
      bf2(a0.z, al, ah); m0 = fmaf(kl, al, m0); m0 = fmaf(kh, ah, m0);
      bf2(a1.z, al, ah); m1 = fmaf(kl, al, m1); m1 = fmaf(kh, ah, m1);
      bf2(ku.w, kl, kh);
      bf2(a0.w, al, ah); m0 = fmaf(kl, al, m0); m0 = fmaf(kh, ah, m0);
      bf2(a1.w, al, ah); m1 = fmaf(kl, al, m1); m1 = fmaf(kh, ah, m1);
    }
    M_t[c2][c1]     = m0;   // M_t[c][o] = M[o][c]
    M_t[c2 + 1][c1] = m1;
  }

  __syncthreads();

  // ---------------- Phase 2.5: G = wq^T * M + I (residual),  g = bq * M -------------
  {
    const int c  = t >> 4;             // 0..31
    const int cp = (t & 15) << 1;      // 0,2,..,30
    float g0 = 0.f, g1 = 0.f;
    #pragma unroll
    for (int o = 0; o < CH; ++o) {
      float m = M_t[c][o];
      g0 = fmaf(wq[o * CH + cp],     m, g0);
      g1 = fmaf(wq[o * CH + cp + 1], m, g1);
    }
    G_t[c][cp]     = g0 + ((cp     == c) ? 1.f : 0.f);
    G_t[c][cp + 1] = g1 + ((cp + 1 == c) ? 1.f : 0.f);
    if (t < CH) {
      float gg = 0.f;
      #pragma unroll
      for (int o = 0; o < CH; ++o) gg = fmaf(bq[o], M_t[t][o], gg);
      g_l[t] = gg;
    }
  }

  __syncthreads();

  // ---------------- Phase 3: out[c][x] = sum_cp q[cp][x] * G[cp][c] + g[c] ----------
  #pragma unroll
  for (int c = 0; c < CH; ++c) col[c] = q[base + (size_t)c * CHST + x];
  #pragma unroll
  for (int c = 0; c < CH; ++c) {
    float acc = g_l[c] + col[c] * 0.f;   // g term; residual is in G's diagonal
    acc = g_l[c];
    #pragma unroll
    for (int cp = 0; cp < CH; ++cp) acc = fmaf(col[cp], G_t[c][cp], acc);
    out[base + (size_t)c * CHST + x] = acc;
  }
}

extern "C" void kernel_launch(void* const* d_in, const int* in_sizes, int n_in,
                              void* d_out, int out_size, void* d_ws, size_t ws_size,
                              hipStream_t stream) {
  const float* q  = (const float*)d_in[0];
  const float* k  = (const float*)d_in[1];
  const float* v  = (const float*)d_in[2];
  const float* wq = (const float*)d_in[3];
  const float* bq = (const float*)d_in[4];
  const float* wk = (const float*)d_in[5];
  const float* bk = (const float*)d_in[6];
  const float* wv = (const float*)d_in[7];
  const float* bv = (const float*)d_in[8];
  float* out = (float*)d_out;

  (void)in_sizes; (void)n_in; (void)out_size; (void)d_ws; (void)ws_size;

  fused_mha<<<dim3(8 * 64), dim3(512), 0, stream>>>(q, k, v, wq, bq, wk, bk, wv, bv, out);
}

// Round 2
// 36.767 us; speedup vs baseline: 2.0144x; 2.0144x over previous
//
#include <hip/hip_runtime.h>
#include <hip/hip_bf16.h>

// Shapes fixed by the reference: B=8, C=32, H=64, W=512, NCHW.
#define CH   32
#define WD   512
#define NH   64
#define CHST (NH * WD)      // channel stride in floats
#define BST  (CH * CHST)    // batch stride in floats
#define ROWP 520            // bf16 LDS row stride: 1040B = 16B-aligned, 4-bank skew

typedef short bf16x8 __attribute__((ext_vector_type(8)));
typedef float f32x16 __attribute__((ext_vector_type(16)));

__device__ __forceinline__ unsigned short f2bf(float f) {
  union { __hip_bfloat16 h; unsigned short u; } cv;
  cv.h = __float2bfloat16(f);
  return cv.u;
}

// kp/vp staging (bf16) overlaid with the M partial-sum buffer (f32) — kp/vp are
// dead by the time partials are written (barrier-separated).
struct SmemKV { unsigned short kp[CH][ROWP]; unsigned short vp[CH][ROWP]; };  // 66560 B
struct SmemMP { float mp[8][CH][33]; };                                       // 33792 B
union  Smem   { SmemKV kv; SmemMP mp; };

// Math per (b,h) block:  kp = Wk*K + bk,  vp = Wv*V + bv   (32x512, bf16 in LDS)
//   M[o][c]  = sum_x kp[o][x] * vp[c][x]                    (32x32, K=512 MFMA)
//   G[cp][c] = sum_o wq[o][cp] * M[o][c]  (+I: residual),  g[c] = sum_o bq[o]*M[o][c]
//   out[c][x] = sum_cp G[cp][c] * q[cp][x] + g[c]           (32x512, K=32 MFMA)
// MFMA 32x32x16 layouts: A: a[j]=A[l&31][8*(l>>5)+j]; B: b[j]=B[8*(l>>5)+j][l&31];
// D: d[r]=D[(r&3)+8*(r>>2)+4*(l>>5)][l&31].
__global__ __launch_bounds__(512, 4)
void fused_mha(const float* __restrict__ qg, const float* __restrict__ kg,
               const float* __restrict__ vg,
               const float* __restrict__ wqg, const float* __restrict__ bqg,
               const float* __restrict__ wkg, const float* __restrict__ bkg,
               const float* __restrict__ wvg, const float* __restrict__ bvg,
               float* __restrict__ outg)
{
  __shared__ Smem sm;
  __shared__ float M_l[CH][33];            // M_l[c][o] = M[o][c]
  __shared__ unsigned short Gb[CH][CH];    // Gb[c][cp] = G[cp][c] + (c==cp), bf16
  __shared__ float g_l[CH];

  const int t    = threadIdx.x;            // 0..511
  const int lane = t & 63;
  const int wid  = t >> 6;                 // wave 0..7
  const int lo   = lane & 31;
  const int hi   = lane >> 5;
  const int bh   = blockIdx.x;             // 0..511
  const size_t base = (size_t)(bh >> 6) * BST + (size_t)(bh & 63) * WD;

  int rowr[16];
  #pragma unroll
  for (int r = 0; r < 16; ++r) rowr[r] = (r & 3) + 8 * (r >> 2) + 4 * hi;

  // ---- A-fragments of Wk, Wv (loop-invariant): a[s][j] = W[lo][16s + 8hi + j]
  bf16x8 wkA[2], wvA[2];
  {
    const float* wk_r = wkg + lo * CH + 8 * hi;
    const float* wv_r = wvg + lo * CH + 8 * hi;
    #pragma unroll
    for (int s = 0; s < 2; ++s)
      #pragma unroll
      for (int j = 0; j < 8; ++j) {
        wkA[s][j] = (short)f2bf(wk_r[16 * s + j]);
        wvA[s][j] = (short)f2bf(wv_r[16 * s + j]);
      }
  }
  float bkr[16], bvr[16];
  #pragma unroll
  for (int r = 0; r < 16; ++r) { bkr[r] = bkg[rowr[r]]; bvr[r] = bvg[rowr[r]]; }

  // ---------------- Step A: kp, vp tiles via MFMA; store bf16 to LDS ----------------
  #pragma unroll
  for (int it = 0; it < 2; ++it) {
    const int x0 = 64 * wid + 32 * it;
    {
      bf16x8 bfr[2];
      #pragma unroll
      for (int s = 0; s < 2; ++s)
        #pragma unroll
        for (int j = 0; j < 8; ++j)
          bfr[s][j] = (short)f2bf(kg[base + (size_t)(16 * s + 8 * hi + j) * CHST + x0 + lo]);
      f32x16 acc;
      #pragma unroll
      for (int r = 0; r < 16; ++r) acc[r] = bkr[r];
      acc = __builtin_amdgcn_mfma_f32_32x32x16_bf16(wkA[0], bfr[0], acc, 0, 0, 0);
      acc = __builtin_amdgcn_mfma_f32_32x32x16_bf16(wkA[1], bfr[1], acc, 0, 0, 0);
      #pragma unroll
      for (int r = 0; r < 16; ++r) sm.kv.kp[rowr[r]][x0 + lo] = f2bf(acc[r]);
    }
    {
      bf16x8 bfr[2];
      #pragma unroll
      for (int s = 0; s < 2; ++s)
        #pragma unroll
        for (int j = 0; j < 8; ++j)
          bfr[s][j] = (short)f2bf(vg[base + (size_t)(16 * s + 8 * hi + j) * CHST + x0 + lo]);
      f32x16 acc;
      #pragma unroll
      for (int r = 0; r < 16; ++r) acc[r] = bvr[r];
      acc = __builtin_amdgcn_mfma_f32_32x32x16_bf16(wvA[0], bfr[0], acc, 0, 0, 0);
      acc = __builtin_amdgcn_mfma_f32_32x32x16_bf16(wvA[1], bfr[1], acc, 0, 0, 0);
      #pragma unroll
      for (int r = 0; r < 16; ++r) sm.kv.vp[rowr[r]][x0 + lo] = f2bf(acc[r]);
    }
  }
  __syncthreads();

  // ---------------- Step B: M = kp * vp^T, K=512 split across 8 waves ---------------
  f32x16 macc;
  #pragma unroll
  for (int r = 0; r < 16; ++r) macc[r] = 0.f;
  #pragma unroll
  for (int kk = 0; kk < 4; ++kk) {
    const int xs = 64 * wid + 16 * kk + 8 * hi;                  // 16B-aligned
    bf16x8 afr = *(const bf16x8*)&sm.kv.kp[lo][xs];              // kp[row=lo][x..]
    bf16x8 bfr = *(const bf16x8*)&sm.kv.vp[lo][xs];              // vp[col=lo][x..]
    macc = __builtin_amdgcn_mfma_f32_32x32x16_bf16(afr, bfr, macc, 0, 0, 0);
  }
  __syncthreads();                       // all kp/vp reads done before overlay write
  #pragma unroll
  for (int r = 0; r < 16; ++r) sm.mp.mp[wid][rowr[r]][lo] = macc[r];
  __syncthreads();

  // ---------------- Reduce 8 partial Ms; store transposed ---------------------------
  {
    int e = t;
    #pragma unroll
    for (int p = 0; p < 2; ++p, e += 512) {
      const int o = e >> 5, c = e & 31;
      float s = 0.f;
      #pragma unroll
      for (int w = 0; w < 8; ++w) s += sm.mp.mp[w][o][c];
      M_l[c][o] = s;
    }
  }
  __syncthreads();

  // ---------------- Step C: G = Wq^T*M + I (bf16), g = bq*M -------------------------
  {
    const int c = t >> 4, cp = (t & 15) << 1;
    float g0 = 0.f, g1 = 0.f;
    #pragma unroll
    for (int o = 0; o < CH; ++o) {
      const float m = M_l[c][o];
      g0 = fmaf(wqg[o * CH + cp],     m, g0);
      g1 = fmaf(wqg[o * CH + cp + 1], m, g1);
    }
    if (cp == c)     g0 += 1.f;
    if (cp + 1 == c) g1 += 1.f;
    const unsigned int packed = ((unsigned)f2bf(g1) << 16) | (unsigned)f2bf(g0);
    *(unsigned int*)&Gb[c][cp] = packed;
    if (t < CH) {
      float gg = 0.f;
      #pragma unroll
      for (int o = 0; o < CH; ++o) gg = fmaf(bqg[o], M_l[t][o], gg);
      g_l[t] = gg;
    }
  }
  __syncthreads();

  // ---------------- Step D: out = (G^T + I) * q_bf16 + g ----------------------------
  {
    bf16x8 gA0 = *(const bf16x8*)&Gb[lo][8 * hi];
    bf16x8 gA1 = *(const bf16x8*)&Gb[lo][16 + 8 * hi];
    float gr[16];
    #pragma unroll
    for (int r = 0; r < 16; ++r) gr[r] = g_l[rowr[r]];
    #pragma unroll
    for (int it = 0; it < 2; ++it) {
      const int x0 = 64 * wid + 32 * it;
      bf16x8 bfr[2];
      #pragma unroll
      for (int s = 0; s < 2; ++s)
        #pragma unroll
        for (int j = 0; j < 8; ++j)
          bfr[s][j] = (short)f2bf(qg[base + (size_t)(16 * s + 8 * hi + j) * CHST + x0 + lo]);
      f32x16 acc;
      #pragma unroll
      for (int r = 0; r < 16; ++r) acc[r] = gr[r];
      acc = __builtin_amdgcn_mfma_f32_32x32x16_bf16(gA0, bfr[0], acc, 0, 0, 0);
      acc = __builtin_amdgcn_mfma_f32_32x32x16_bf16(gA1, bfr[1], acc, 0, 0, 0);
      #pragma unroll
      for (int r = 0; r < 16; ++r)
        outg[base + (size_t)rowr[r] * CHST + x0 + lo] = acc[r];
    }
  }
}

extern "C" void kernel_launch(void* const* d_in, const int* in_sizes, int n_in,
                              void* d_out, int out_size, void* d_ws, size_t ws_size,
                              hipStream_t stream) {
  const float* q  = (const float*)d_in[0];
  const float* k  = (const float*)d_in[1];
  const float* v  = (const float*)d_in[2];
  const float* wq = (const float*)d_in[3];
  const float* bq = (const float*)d_in[4];
  const float* wk = (const float*)d_in[5];
  const float* bk = (const float*)d_in[6];
  const float* wv = (const float*)d_in[7];
  const float* bv = (const float*)d_in[8];
  float* out = (float*)d_out;

  (void)in_sizes; (void)n_in; (void)out_size; (void)d_ws; (void)ws_size;

  fused_mha<<<dim3(8 * 64), dim3(512), 0, stream>>>(q, k, v, wq, bq, wk, bk, wv, bv, out);
}

// Round 3
// 31.642 us; speedup vs baseline: 2.3407x; 1.1620x over previous
//
#include <hip/hip_runtime.h>
#include <hip/hip_bf16.h>

// Shapes fixed by the reference: B=8, C=32, H=64, W=512, NCHW.
#define CH   32
#define WD   512
#define NH   64
#define CHST (NH * WD)      // channel stride in floats
#define BST  (CH * CHST)    // batch stride in floats
#define ROWB 1040           // bytes per LDS row (520 bf16; 16B-aligned)

typedef short bf16x8 __attribute__((ext_vector_type(8)));
typedef float f32x16 __attribute__((ext_vector_type(16)));

__device__ __forceinline__ unsigned short f2bf(float f) {
  union { __hip_bfloat16 h; unsigned short u; } cv;
  cv.h = __float2bfloat16(f);
  return cv.u;
}
__device__ __forceinline__ unsigned int pk2(float lo_, float hi_) {
  return ((unsigned int)f2bf(hi_) << 16) | (unsigned int)f2bf(lo_);
}
// v_permlane32_swap_b32 a, b:  a' = [a_lo32 | b_lo32],  b' = [a_hi32 | b_hi32]
__device__ __forceinline__ void swap32(unsigned int& a, unsigned int& b) {
  asm volatile("v_permlane32_swap_b32 %0, %1" : "+v"(a), "+v"(b));
}

union W4 { unsigned int u[4]; bf16x8 v; };

// One block per (b,h). Single barrier. All waves hold full M redundantly.
// Math: kp=Wk*K+bk, vp=Wv*V+bv (bf16 LDS, swizzled); M[o][c]=sum_x kp[o][x]vp[c][x];
//       G=Wq^T*M (+I residual); g=bq*M; out[c][x]=sum_cp G[cp][c]*q[cp][x]+g[c].
// MFMA 32x32x16: A: a[j]=A[lo][16s+8hi+j]; B: b[j]=B[16s+8hi+j][lo];
// D: d[r]=D[(r&3)+8(r>>2)+4hi][lo].  D->B/A-frag done via pk2+permlane32_swap.
__global__ __launch_bounds__(512, 4)
void fused_mha(const float* __restrict__ qg, const float* __restrict__ kg,
               const float* __restrict__ vg,
               const float* __restrict__ wqg, const float* __restrict__ bqg,
               const float* __restrict__ wkg, const float* __restrict__ bkg,
               const float* __restrict__ wvg, const float* __restrict__ bvg,
               float* __restrict__ outg)
{
  __shared__ __align__(16) char kpL[CH * ROWB];
  __shared__ __align__(16) char vpL[CH * ROWB];

  const int t = threadIdx.x, lane = t & 63, wid = t >> 6;
  const int lo = lane & 31, hi = lane >> 5;
  const int bh = blockIdx.x;
  const size_t base = (size_t)(bh >> 6) * BST + (size_t)(bh & 63) * WD;

  int rowr[16];
  #pragma unroll
  for (int r = 0; r < 16; ++r) rowr[r] = (r & 3) + 8 * (r >> 2) + 4 * hi;

  // ---- Wk/Wv A-fragments + biases (loop-invariant) --------------------------------
  bf16x8 wkA[2], wvA[2];
  {
    const float* wk_r = wkg + lo * CH + 8 * hi;
    const float* wv_r = wvg + lo * CH + 8 * hi;
    #pragma unroll
    for (int s = 0; s < 2; ++s)
      #pragma unroll
      for (int j = 0; j < 8; ++j) {
        wkA[s][j] = (short)f2bf(wk_r[16 * s + j]);
        wvA[s][j] = (short)f2bf(wv_r[16 * s + j]);
      }
  }
  float bkr[16], bvr[16];
  #pragma unroll
  for (int r = 0; r < 16; ++r) { bkr[r] = bkg[rowr[r]]; bvr[r] = bvg[rowr[r]]; }

  // ---- Step A: project k,v -> kp,vp (bf16, swizzled LDS) --------------------------
  #pragma unroll
  for (int it = 0; it < 2; ++it) {
    const int x0 = 64 * wid + 32 * it;
    float kf[16], vf[16];
    #pragma unroll
    for (int s = 0; s < 2; ++s)
      #pragma unroll
      for (int j = 0; j < 8; ++j) {
        kf[8 * s + j] = kg[base + (size_t)(16 * s + 8 * hi + j) * CHST + x0 + lo];
        vf[8 * s + j] = vg[base + (size_t)(16 * s + 8 * hi + j) * CHST + x0 + lo];
      }
    bf16x8 kb[2], vb[2];
    #pragma unroll
    for (int s = 0; s < 2; ++s)
      #pragma unroll
      for (int j = 0; j < 8; ++j) {
        kb[s][j] = (short)f2bf(kf[8 * s + j]);
        vb[s][j] = (short)f2bf(vf[8 * s + j]);
      }
    f32x16 ka, va;
    #pragma unroll
    for (int r = 0; r < 16; ++r) { ka[r] = bkr[r]; va[r] = bvr[r]; }
    ka = __builtin_amdgcn_mfma_f32_32x32x16_bf16(wkA[0], kb[0], ka, 0, 0, 0);
    ka = __builtin_amdgcn_mfma_f32_32x32x16_bf16(wkA[1], kb[1], ka, 0, 0, 0);
    va = __builtin_amdgcn_mfma_f32_32x32x16_bf16(wvA[0], vb[0], va, 0, 0, 0);
    va = __builtin_amdgcn_mfma_f32_32x32x16_bf16(wvA[1], vb[1], va, 0, 0, 0);
    #pragma unroll
    for (int r = 0; r < 16; ++r) {
      const int row = rowr[r];
      const int off = row * ROWB + ((((x0 + lo) << 1)) ^ (((row >> 3) & 3) << 4));
      *(unsigned short*)(kpL + off) = f2bf(ka[r]);
      *(unsigned short*)(vpL + off) = f2bf(va[r]);
    }
  }

  // ---- Wq A-fragment: issue loads before the barrier ------------------------------
  bf16x8 wqA[2];
  {
    float wqf[16];
    #pragma unroll
    for (int s = 0; s < 2; ++s)
      #pragma unroll
      for (int j = 0; j < 8; ++j)
        wqf[8 * s + j] = wqg[(16 * s + 8 * hi + j) * CH + lo];
    #pragma unroll
    for (int s = 0; s < 2; ++s)
      #pragma unroll
      for (int j = 0; j < 8; ++j)
        wqA[s][j] = (short)f2bf(wqf[8 * s + j]);
  }

  __syncthreads();   // the only barrier

  // ---- q prefetch: latency hides under Step B's ds_read/MFMA chain ---------------
  float qpf[32];
  #pragma unroll
  for (int it = 0; it < 2; ++it)
    #pragma unroll
    for (int s = 0; s < 2; ++s)
      #pragma unroll
      for (int j = 0; j < 8; ++j)
        qpf[16 * it + 8 * s + j] =
            qg[base + (size_t)(16 * s + 8 * hi + j) * CHST + 64 * wid + 32 * it + lo];

  // ---- Step B: M = kp * vp^T over full K=512 (per-wave, redundant) ----------------
  const int swzlo = ((lo >> 3) & 3) << 4;
  f32x16 macc;
  #pragma unroll
  for (int r = 0; r < 16; ++r) macc[r] = 0.f;
  #pragma unroll
  for (int kk = 0; kk < 32; ++kk) {
    const int off = lo * ROWB + ((32 * kk + 16 * hi) ^ swzlo);
    bf16x8 afr = *(const bf16x8*)(kpL + off);
    bf16x8 bfr = *(const bf16x8*)(vpL + off);
    macc = __builtin_amdgcn_mfma_f32_32x32x16_bf16(afr, bfr, macc, 0, 0, 0);
  }

  float bqr[16];
  #pragma unroll
  for (int r = 0; r < 16; ++r) bqr[r] = bqg[rowr[r]];

  // ---- D-layout macc -> B-fragments of M (pack + permlane swap) -------------------
  W4 mb0, mb1;
  mb0.u[0] = pk2(macc[0], macc[1]);  mb0.u[1] = pk2(macc[2],  macc[3]);
  mb0.u[2] = pk2(macc[4], macc[5]);  mb0.u[3] = pk2(macc[6],  macc[7]);
  swap32(mb0.u[0], mb0.u[2]);        swap32(mb0.u[1], mb0.u[3]);
  mb1.u[0] = pk2(macc[8], macc[9]);  mb1.u[1] = pk2(macc[10], macc[11]);
  mb1.u[2] = pk2(macc[12], macc[13]); mb1.u[3] = pk2(macc[14], macc[15]);
  swap32(mb1.u[0], mb1.u[2]);        swap32(mb1.u[1], mb1.u[3]);

  // ---- Step C: G = Wq^T * M (+I), g = bq * M --------------------------------------
  f32x16 gacc;
  #pragma unroll
  for (int r = 0; r < 16; ++r) gacc[r] = 0.f;
  gacc = __builtin_amdgcn_mfma_f32_32x32x16_bf16(wqA[0], mb0.v, gacc, 0, 0, 0);
  gacc = __builtin_amdgcn_mfma_f32_32x32x16_bf16(wqA[1], mb1.v, gacc, 0, 0, 0);
  #pragma unroll
  for (int r = 0; r < 16; ++r)
    if (rowr[r] == lo) gacc[r] += 1.f;          // residual: +I on G's diagonal

  float part = 0.f;
  #pragma unroll
  for (int r = 0; r < 16; ++r) part = fmaf(bqr[r], macc[r], part);
  unsigned int pa = __float_as_uint(part), pb = pa;
  swap32(pa, pb);                                // pa=[p_lo|p_lo], pb=[p_hi|p_hi]
  const float gv = __uint_as_float(pa) + __uint_as_float(pb);   // g[lo], all lanes

  // ---- G (D-layout) -> A-fragments ------------------------------------------------
  W4 ga0, ga1;
  ga0.u[0] = pk2(gacc[0], gacc[1]);   ga0.u[1] = pk2(gacc[2],  gacc[3]);
  ga0.u[2] = pk2(gacc[4], gacc[5]);   ga0.u[3] = pk2(gacc[6],  gacc[7]);
  swap32(ga0.u[0], ga0.u[2]);         swap32(ga0.u[1], ga0.u[3]);
  ga1.u[0] = pk2(gacc[8], gacc[9]);   ga1.u[1] = pk2(gacc[10], gacc[11]);
  ga1.u[2] = pk2(gacc[12], gacc[13]); ga1.u[3] = pk2(gacc[14], gacc[15]);
  swap32(ga1.u[0], ga1.u[2]);         swap32(ga1.u[1], ga1.u[3]);

  float gsh[16];
  #pragma unroll
  for (int r = 0; r < 16; ++r) gsh[r] = __shfl(gv, rowr[r], 64);

  // ---- Step D: out = (G+I)^T * q_bf16 + g -----------------------------------------
  #pragma unroll
  for (int it = 0; it < 2; ++it) {
    const int x0 = 64 * wid + 32 * it;
    bf16x8 qb[2];
    #pragma unroll
    for (int s = 0; s < 2; ++s)
      #pragma unroll
      for (int j = 0; j < 8; ++j)
        qb[s][j] = (short)f2bf(qpf[16 * it + 8 * s + j]);
    f32x16 acc;
    #pragma unroll
    for (int r = 0; r < 16; ++r) acc[r] = gsh[r];
    acc = __builtin_amdgcn_mfma_f32_32x32x16_bf16(ga0.v, qb[0], acc, 0, 0, 0);
    acc = __builtin_amdgcn_mfma_f32_32x32x16_bf16(ga1.v, qb[1], acc, 0, 0, 0);
    #pragma unroll
    for (int r = 0; r < 16; ++r)
      outg[base + (size_t)rowr[r] * CHST + x0 + lo] = acc[r];
  }
}

extern "C" void kernel_launch(void* const* d_in, const int* in_sizes, int n_in,
                              void* d_out, int out_size, void* d_ws, size_t ws_size,
                              hipStream_t stream) {
  const float* q  = (const float*)d_in[0];
  const float* k  = (const float*)d_in[1];
  const float* v  = (const float*)d_in[2];
  const float* wq = (const float*)d_in[3];
  const float* bq = (const float*)d_in[4];
  const float* wk = (const float*)d_in[5];
  const float* bk = (const float*)d_in[6];
  const float* wv = (const float*)d_in[7];
  const float* bv = (const float*)d_in[8];
  float* out = (float*)d_out;

  (void)in_sizes; (void)n_in; (void)out_size; (void)d_ws; (void)ws_size;

  fused_mha<<<dim3(8 * 64), dim3(512), 0, stream>>>(q, k, v, wq, bq, wk, bk, wv, bv, out);
}